// Round 8
// baseline (1075.535 us; speedup 1.0000x reference)
//
#include <hip/hip_runtime.h>
#include <hip/hip_bf16.h>

// UpBlock: 5 sparse gather-GEMM convs + LeakyReLU + BatchNorm + residual.
// R6: deep global_load_lds pipeline. A-gathers depth-6 per-wave LDS slots,
// W depth-4 block-shared (staged 3 subtaps ahead so W-waits never drain the
// A pipeline), one counted vmcnt + one raw s_barrier per subtap.

typedef __attribute__((ext_vector_type(8))) short bf16x8;
typedef __attribute__((ext_vector_type(4))) float f32x4;

__device__ __forceinline__ short f2bf(float f) {
    union { float f; unsigned u; } v; v.f = f;
    unsigned r = v.u + 0x7fffu + ((v.u >> 16) & 1u);
    return (short)(r >> 16);
}
__device__ __forceinline__ float bf2f(short s) {
    union { unsigned u; float f; } v;
    v.u = ((unsigned)(unsigned short)s) << 16;
    return v.f;
}

__device__ __forceinline__ void gload16(const void* g, void* l) {
    __builtin_amdgcn_global_load_lds(
        (const __attribute__((address_space(1))) char*)g,
        (__attribute__((address_space(3))) char*)l, 16, 0, 0);
}

// ---------------- cast fp32 -> bf16 ----------------
__global__ void cast_kernel(const float* __restrict__ in, short* __restrict__ out, int total) {
    int e = (blockIdx.x * blockDim.x + threadIdx.x) * 8;
    if (e >= total) return;
    bf16x8 r;
#pragma unroll
    for (int j = 0; j < 8; ++j) r[j] = f2bf(in[e + j]);
    *(bf16x8*)(out + e) = r;
}

// ---- pack W[k][ci][co] -> Wp[tap'][co][ci'] bf16 (tap' = CI-64 sub-tap) ----
template <int H>  // H = CI/64
__global__ void pack_w_kernel(const float* __restrict__ w, short* __restrict__ wp,
                              const float* __restrict__ ss, int total) {
    int t = blockIdx.x * blockDim.x + threadIdx.x;
    if (t >= total) return;
    int ci2 = t & 63;
    int co = (t >> 6) & 63;
    int tap = t >> 12;
    int k = tap / H, half = tap % H;
    int ci = half * 64 + ci2;
    float v = w[(k * (64 * H) + ci) * 64 + co];
    if (ss) v *= ss[ci];
    wp[t] = f2bf(v);
}

// ------ bias[co] += sum_ci sh[ci]*W[k][ci][co]; one block per tap k ------
__global__ void bias_kernel(const float* __restrict__ w, const float* __restrict__ ss,
                            int CI, float* __restrict__ bias) {
    int k = blockIdx.x;
    int co = threadIdx.x;
    float acc = 0.f;
    for (int ci = 0; ci < CI; ++ci)
        acc += ss[64 + ci] * w[(k * CI + ci) * 64 + co];
    atomicAdd(&bias[co], acc);
}

// ================= gather-GEMM conv =================
template <int KTAB, int H>
struct CC {
    static constexpr int KT2 = KTAB * H;
    const char* finb;
    const char* wpb;
    const int* snbr;
    char* aslot;      // my wave's 6 A slots (6 x 4 KB)
    char* wbuf;       // 4 W slots (4 x 8 KB), block-shared
    int row0, row1;
    int lg16;         // lg*16
    int wsrc;         // wid*2048 + per-lane inverse-swizzle src offset
    int wdst;         // wid*2048 (uniform LDS part of W stage)
    int CIB;
};

// stage W sub-tap tw into wbuf slot tw&3 (2 insts/wave, 4 waves = 8 KB)
template <int tw, int KTAB, int H>
__device__ __forceinline__ void issue_w(const CC<KTAB, H>& c) {
    const char* s = c.wpb + (size_t)tw * 8192 + c.wsrc;
    char* d = c.wbuf + (tw & 3) * 8192 + c.wdst;
    gload16(s, d);
    gload16(s + 1024, d + 1024);
}

// gather A sub-tap ta into my slot ta%6 (4 insts: 2 row-tiles x 2 k-chunks)
template <int ta, int KTAB, int H>
__device__ __forceinline__ void issue_a(const CC<KTAB, H>& c) {
    constexpr int k = (H == 2) ? (ta >> 1) : ta;
    constexpr int hoff = (H == 2) ? ((ta & 1) * 128) : 0;
    int i0 = c.snbr[c.row0 * KTAB + k];
    int i1 = c.snbr[c.row1 * KTAB + k];
    const char* b0 = c.finb + (size_t)i0 * c.CIB + hoff + c.lg16;
    const char* b1 = c.finb + (size_t)i1 * c.CIB + hoff + c.lg16;
    char* d = c.aslot + (ta % 6) * 4096;
    gload16(b0,      d);
    gload16(b0 + 64, d + 1024);
    gload16(b1,      d + 2048);
    gload16(b1 + 64, d + 3072);
}

// Event order: prologue [W0 W1 W2 | A0..A5]; body t issues W(t+3) then A(t+6).
// Wait at body t needs W(t) (issued body t-3) and A(t) (older). Younger set:
// A(t+3),W(t+1),A(t+4),W(t+2),A(t+5) -> NW = 4*3 + 2*2 = 16 steady.
template <int t, int KTAB, int H>
__device__ __forceinline__ void body(const CC<KTAB, H>& c, int lane, int lr,
                                     int wk0, int wk1, f32x4 (&acc)[2][4]) {
    constexpr int KT2 = CC<KTAB, H>::KT2;
    constexpr int NW =
        (t == 0) ? 20 : (t == 1) ? 22 : (t == 2) ? 24 :
        4 * (((t + 3 < KT2) ? 1 : 0) + ((t + 4 < KT2) ? 1 : 0) + ((t + 5 < KT2) ? 1 : 0)) +
        2 * (((t + 1 < KT2) ? 1 : 0) + ((t + 2 < KT2) ? 1 : 0));
    asm volatile("s_waitcnt vmcnt(%0)" :: "i"(NW) : "memory");
    __builtin_amdgcn_sched_barrier(0);
    __builtin_amdgcn_s_barrier();
    __builtin_amdgcn_sched_barrier(0);
    if constexpr (t + 3 < KT2) issue_w<t + 3>(c);

    // reads (compiler ds_read_b128, conflict-free / 2-way max)
    const char* as = c.aslot + (t % 6) * 4096 + lane * 16;
    bf16x8 a0 = *(const bf16x8*)(as);
    bf16x8 a1 = *(const bf16x8*)(as + 1024);
    bf16x8 a2 = *(const bf16x8*)(as + 2048);
    bf16x8 a3 = *(const bf16x8*)(as + 3072);
    const char* wsb = c.wbuf + (t & 3) * 8192 + lr * 128;
    bf16x8 w0[4], w1[4];
#pragma unroll
    for (int ct = 0; ct < 4; ++ct) {
        w0[ct] = *(const bf16x8*)(wsb + ct * 2048 + wk0);
        w1[ct] = *(const bf16x8*)(wsb + ct * 2048 + wk1);
    }
    asm volatile("s_waitcnt lgkmcnt(0)" ::: "memory");
    __builtin_amdgcn_sched_barrier(0);
    if constexpr (t + 6 < KT2) issue_a<t + 6>(c);

#pragma unroll
    for (int ct = 0; ct < 4; ++ct) {
        acc[0][ct] = __builtin_amdgcn_mfma_f32_16x16x32_bf16(a0, w0[ct], acc[0][ct], 0, 0, 0);
        acc[0][ct] = __builtin_amdgcn_mfma_f32_16x16x32_bf16(a1, w1[ct], acc[0][ct], 0, 0, 0);
        acc[1][ct] = __builtin_amdgcn_mfma_f32_16x16x32_bf16(a2, w0[ct], acc[1][ct], 0, 0, 0);
        acc[1][ct] = __builtin_amdgcn_mfma_f32_16x16x32_bf16(a3, w1[ct], acc[1][ct], 0, 0, 0);
    }
    if constexpr (t + 1 < KT2) body<t + 1>(c, lane, lr, wk0, wk1, acc);
}

// MODE 0: leaky(acc[+bias]) -> bf16 + fused stats. MODE 1: acc+bias+skip -> bf16.
template <int KTAB, int H, int MODE, bool HAS_BIAS>
__global__ __launch_bounds__(256, 1) void conv_kernel(
    const short* __restrict__ fin, const int* __restrict__ nbr,
    const short* __restrict__ wp, const float* __restrict__ bias,
    const float* __restrict__ skip, short* __restrict__ fout,
    int N, float* __restrict__ sums)
{
    __shared__ int snbr[128 * KTAB];
    __shared__ __align__(16) char wbuf[4 * 8192];
    __shared__ __align__(16) char abuf[4][6 * 4096];
    __shared__ float sred[128];

    const int tid = threadIdx.x;
    const int lane = tid & 63;
    const int wid = tid >> 6;
    const int lr = lane & 15;
    const int lg = lane >> 4;
    const int rowbase = blockIdx.x * 128;
    const int nrows = (N - rowbase < 128) ? (N - rowbase) : 128;

    for (int i = tid; i < nrows * KTAB; i += 256)
        snbr[i] = __builtin_nontemporal_load(&nbr[(size_t)rowbase * KTAB + i]);
    if (MODE == 0 && tid < 128) sred[tid] = 0.f;
    __syncthreads();   // full drain: vmcnt accounting starts clean

    const int rb0 = wid * 32 + lr;
    const int rb1 = wid * 32 + 16 + lr;

    CC<KTAB, H> c;
    c.finb = (const char*)fin;
    c.wpb = (const char*)wp;
    c.snbr = snbr;
    c.aslot = &abuf[wid][0];
    c.wbuf = wbuf;
    c.row0 = (rb0 < nrows ? rb0 : nrows - 1);
    c.row1 = (rb1 < nrows ? rb1 : nrows - 1);
    c.lg16 = lg * 16;
    // W stage: lane writes LDS phys (lane*16); logical source undoes XOR swizzle
    c.wsrc = wid * 2048 + (lane >> 3) * 128 + (((lane & 7) ^ ((lane >> 3) & 7)) << 4);
    c.wdst = wid * 2048;
    c.CIB = 64 * H * 2;

    // W read offsets: frag (ct,kc) at co*128 + ((kc*4+lg)^(lr&7))*16
    const int wk0 = ((lg) ^ (lr & 7)) << 4;
    const int wk1 = ((4 + lg) ^ (lr & 7)) << 4;

    f32x4 acc[2][4];
#pragma unroll
    for (int q = 0; q < 2; ++q)
#pragma unroll
        for (int ct = 0; ct < 4; ++ct) acc[q][ct] = (f32x4)(0.f);

    // prologue: W0 W1 W2, A0..A5
    issue_w<0>(c); issue_w<1>(c); issue_w<2>(c);
    issue_a<0>(c); issue_a<1>(c); issue_a<2>(c);
    issue_a<3>(c); issue_a<4>(c); issue_a<5>(c);
    body<0>(c, lane, lr, wk0, wk1, acc);

    // ---------------- epilogue ----------------
    float bia[4] = {0.f, 0.f, 0.f, 0.f};
    if (HAS_BIAS) {
#pragma unroll
        for (int ct = 0; ct < 4; ++ct) bia[ct] = bias[ct * 16 + lr];
    }
    float bsum[4] = {0.f, 0.f, 0.f, 0.f};
    float bsq[4] = {0.f, 0.f, 0.f, 0.f};
    const int wrow = wid * 32;
#pragma unroll
    for (int q = 0; q < 2; ++q) {
#pragma unroll
        for (int reg = 0; reg < 4; ++reg) {
            const int r = rowbase + wrow + q * 16 + lg * 4 + reg;
            const bool valid = r < N;
#pragma unroll
            for (int ct = 0; ct < 4; ++ct) {
                float v = acc[q][ct][reg];
                if (HAS_BIAS) v += bia[ct];
                if (MODE == 0) {
                    v = v > 0.f ? v : 0.01f * v;
                    if (valid) {
                        fout[(size_t)r * 64 + ct * 16 + lr] = f2bf(v);
                        bsum[ct] += v;
                        bsq[ct] += v * v;
                    }
                } else {
                    if (valid) {
                        v += skip[(size_t)r * 64 + ct * 16 + lr];
                        fout[(size_t)r * 64 + ct * 16 + lr] = f2bf(v);
                    }
                }
            }
        }
    }

    if (MODE == 0) {
#pragma unroll
        for (int ct = 0; ct < 4; ++ct) {
            float s = bsum[ct], q = bsq[ct];
            s += __shfl_xor(s, 16); s += __shfl_xor(s, 32);
            q += __shfl_xor(q, 16); q += __shfl_xor(q, 32);
            if (lg == 0) {
                atomicAdd(&sred[ct * 16 + lr], s);
                atomicAdd(&sred[64 + ct * 16 + lr], q);
            }
        }
        __syncthreads();
        if (tid < 128) atomicAdd(&sums[tid], sred[tid]);
    }
}

// -------------- BN scale/shift from sums --------------
__global__ void finalize_kernel(const float* __restrict__ sums, const float* __restrict__ g,
                                const float* __restrict__ b, float invN, float* __restrict__ ss) {
    int c = threadIdx.x;
    float mean = sums[c] * invN;
    float var = sums[64 + c] * invN - mean * mean;
    float sc = g[c] * rsqrtf(var + 1e-5f);
    ss[c] = sc;
    ss[64 + c] = b[c] - mean * sc;
}

// -------------- final BN apply -> fp32 output --------------
__global__ void final_norm_kernel(const short* __restrict__ in, const float* __restrict__ ss,
                                  float* __restrict__ out, int total) {
    int e = (blockIdx.x * blockDim.x + threadIdx.x) * 8;
    if (e >= total) return;
    bf16x8 v = *(const bf16x8*)(in + e);
    int c0 = e & 63;
#pragma unroll
    for (int j = 0; j < 8; ++j)
        out[e + j] = bf2f(v[j]) * ss[c0 + j] + ss[64 + c0 + j];
}

extern "C" void kernel_launch(void* const* d_in, const int* in_sizes, int n_in,
                              void* d_out, int out_size, void* d_ws, size_t ws_size,
                              hipStream_t stream) {
    const float* x    = (const float*)d_in[0];
    const float* skip = (const float*)d_in[1];
    const int* nbr1 = (const int*)d_in[2];
    const int* nbrU = (const int*)d_in[3];
    const int* nbr2 = (const int*)d_in[4];
    const int* nbr3 = (const int*)d_in[5];
    const int* nbr4 = (const int*)d_in[6];
    const float* W1 = (const float*)d_in[7];
    const float* WU = (const float*)d_in[8];
    const float* W2 = (const float*)d_in[9];
    const float* W3 = (const float*)d_in[10];
    const float* W4 = (const float*)d_in[11];
    const float* g1 = (const float*)d_in[12]; const float* b1 = (const float*)d_in[13];
    const float* g2 = (const float*)d_in[14]; const float* b2 = (const float*)d_in[15];
    const float* g3 = (const float*)d_in[16]; const float* b3 = (const float*)d_in[17];
    const float* g4 = (const float*)d_in[18]; const float* b4 = (const float*)d_in[19];

    const int Nl = in_sizes[0] / 128;  // 120000
    const int Nu = in_sizes[1] / 64;   // 240000

    char* ws = (char*)d_ws;
    size_t off = 0;
    auto alloc = [&](size_t bytes) -> char* {
        char* p = ws + off;
        off += (bytes + 255) & ~(size_t)255;
        return p;
    };
    const size_t fbig = (size_t)Nu * 64 * 2;
    const size_t xb = (size_t)Nl * 128 * 2;
    short* A = (short*)alloc(xb > fbig ? xb : fbig);
    short* B = (short*)alloc(fbig);
    short* C = (short*)alloc(fbig);
    short* Wp1 = (short*)alloc((size_t)54 * 8192);
    short* WpU = (short*)alloc((size_t)27 * 8192);
    short* Wp2 = (short*)alloc((size_t)9 * 8192);
    short* Wp3 = (short*)alloc((size_t)9 * 8192);
    short* Wp4 = (short*)alloc((size_t)27 * 8192);
    float* sums = (float*)alloc((512 + 192) * sizeof(float));
    float* biasU = sums + 512;
    float* bias3 = sums + 576;
    float* bias4 = sums + 640;
    float* ss = (float*)alloc(4 * 128 * sizeof(float));

    hipMemsetAsync(sums, 0, (512 + 192) * sizeof(float), stream);

    cast_kernel<<<(Nl * 128 / 8 + 255) / 256, 256, 0, stream>>>(x, A, Nl * 128);
    pack_w_kernel<2><<<(54 * 4096 + 255) / 256, 256, 0, stream>>>(W1, Wp1, nullptr, 54 * 4096);
    pack_w_kernel<1><<<(9 * 4096 + 255) / 256, 256, 0, stream>>>(W2, Wp2, nullptr, 9 * 4096);

    const int gl = (Nl + 127) / 128;
    const int gu = (Nu + 127) / 128;

    // stage 1: conv1 (CI=128 -> H=2, K=27) + leaky + stats  [A -> B]
    conv_kernel<27, 2, 0, false><<<gl, 256, 0, stream>>>(A, nbr1, Wp1, nullptr, nullptr, B, Nl, sums + 0);
    finalize_kernel<<<1, 64, 0, stream>>>(sums + 0, g1, b1, 1.f / Nl, ss + 0);
    pack_w_kernel<1><<<(27 * 4096 + 255) / 256, 256, 0, stream>>>(WU, WpU, ss + 0, 27 * 4096);
    bias_kernel<<<27, 64, 0, stream>>>(WU, ss + 0, 64, biasU);

    // stage 2: inverse conv (K=27) + bias + skip  [B -> C]
    conv_kernel<27, 1, 1, true><<<gu, 256, 0, stream>>>(B, nbrU, WpU, biasU, skip, C, Nu, nullptr);

    // stage 3: conv2 (K=9) + leaky + stats  [C -> A]
    conv_kernel<9, 1, 0, false><<<gu, 256, 0, stream>>>(C, nbr2, Wp2, nullptr, nullptr, A, Nu, sums + 128);
    finalize_kernel<<<1, 64, 0, stream>>>(sums + 128, g2, b2, 1.f / Nu, ss + 128);
    pack_w_kernel<1><<<(9 * 4096 + 255) / 256, 256, 0, stream>>>(W3, Wp3, ss + 128, 9 * 4096);
    bias_kernel<<<9, 64, 0, stream>>>(W3, ss + 128, 64, bias3);

    // stage 4: conv3 (K=9) + bias + leaky + stats  [A -> B]
    conv_kernel<9, 1, 0, true><<<gu, 256, 0, stream>>>(A, nbr3, Wp3, bias3, nullptr, B, Nu, sums + 256);
    finalize_kernel<<<1, 64, 0, stream>>>(sums + 256, g3, b3, 1.f / Nu, ss + 256);
    pack_w_kernel<1><<<(27 * 4096 + 255) / 256, 256, 0, stream>>>(W4, Wp4, ss + 256, 27 * 4096);
    bias_kernel<<<27, 64, 0, stream>>>(W4, ss + 256, 64, bias4);

    // stage 5: conv4 (K=27) + bias + leaky + stats  [B -> C]
    conv_kernel<27, 1, 0, true><<<gu, 256, 0, stream>>>(B, nbr4, Wp4, bias4, nullptr, C, Nu, sums + 384);
    finalize_kernel<<<1, 64, 0, stream>>>(sums + 384, g4, b4, 1.f / Nu, ss + 384);

    final_norm_kernel<<<(Nu * 64 / 8 + 255) / 256, 256, 0, stream>>>(C, ss + 384, (float*)d_out, Nu * 64);
}

// Round 9
// 1071.673 us; speedup vs baseline: 1.0036x; 1.0036x over previous
//
#include <hip/hip_runtime.h>
#include <hip/hip_bf16.h>

// UpBlock: 5 sparse gather-GEMM convs + LeakyReLU + BatchNorm + residual.
// R6: deep global_load_lds pipeline. A-gathers depth-6 per-wave LDS slots,
// W depth-4 block-shared (staged 3 subtaps ahead so W-waits never drain the
// A pipeline), one counted vmcnt + one raw s_barrier per subtap.

typedef __attribute__((ext_vector_type(8))) short bf16x8;
typedef __attribute__((ext_vector_type(4))) float f32x4;

__device__ __forceinline__ short f2bf(float f) {
    union { float f; unsigned u; } v; v.f = f;
    unsigned r = v.u + 0x7fffu + ((v.u >> 16) & 1u);
    return (short)(r >> 16);
}
__device__ __forceinline__ float bf2f(short s) {
    union { unsigned u; float f; } v;
    v.u = ((unsigned)(unsigned short)s) << 16;
    return v.f;
}

__device__ __forceinline__ void gload16(const void* g, void* l) {
    __builtin_amdgcn_global_load_lds(
        (const __attribute__((address_space(1))) char*)g,
        (__attribute__((address_space(3))) char*)l, 16, 0, 0);
}

// ---------------- cast fp32 -> bf16 ----------------
__global__ void cast_kernel(const float* __restrict__ in, short* __restrict__ out, int total) {
    int e = (blockIdx.x * blockDim.x + threadIdx.x) * 8;
    if (e >= total) return;
    bf16x8 r;
#pragma unroll
    for (int j = 0; j < 8; ++j) r[j] = f2bf(in[e + j]);
    *(bf16x8*)(out + e) = r;
}

// ---- pack W[k][ci][co] -> Wp[tap'][co][ci'] bf16 (tap' = CI-64 sub-tap) ----
template <int H>  // H = CI/64
__global__ void pack_w_kernel(const float* __restrict__ w, short* __restrict__ wp,
                              const float* __restrict__ ss, int total) {
    int t = blockIdx.x * blockDim.x + threadIdx.x;
    if (t >= total) return;
    int ci2 = t & 63;
    int co = (t >> 6) & 63;
    int tap = t >> 12;
    int k = tap / H, half = tap % H;
    int ci = half * 64 + ci2;
    float v = w[(k * (64 * H) + ci) * 64 + co];
    if (ss) v *= ss[ci];
    wp[t] = f2bf(v);
}

// ------ bias[co] += sum_ci sh[ci]*W[k][ci][co]; one block per tap k ------
__global__ void bias_kernel(const float* __restrict__ w, const float* __restrict__ ss,
                            int CI, float* __restrict__ bias) {
    int k = blockIdx.x;
    int co = threadIdx.x;
    float acc = 0.f;
    for (int ci = 0; ci < CI; ++ci)
        acc += ss[64 + ci] * w[(k * CI + ci) * 64 + co];
    atomicAdd(&bias[co], acc);
}

// ================= gather-GEMM conv =================
template <int KTAB, int H>
struct CC {
    static constexpr int KT2 = KTAB * H;
    const char* finb;
    const char* wpb;
    const int* snbr;
    char* aslot;      // my wave's 6 A slots (6 x 4 KB)
    char* wbuf;       // 4 W slots (4 x 8 KB), block-shared
    int row0, row1;
    int lg16;         // lg*16
    int wsrc;         // wid*2048 + per-lane inverse-swizzle src offset
    int wdst;         // wid*2048 (uniform LDS part of W stage)
    int CIB;
};

// stage W sub-tap tw into wbuf slot tw&3 (2 insts/wave, 4 waves = 8 KB)
template <int tw, int KTAB, int H>
__device__ __forceinline__ void issue_w(const CC<KTAB, H>& c) {
    const char* s = c.wpb + (size_t)tw * 8192 + c.wsrc;
    char* d = c.wbuf + (tw & 3) * 8192 + c.wdst;
    gload16(s, d);
    gload16(s + 1024, d + 1024);
}

// gather A sub-tap ta into my slot ta%6 (4 insts: 2 row-tiles x 2 k-chunks)
template <int ta, int KTAB, int H>
__device__ __forceinline__ void issue_a(const CC<KTAB, H>& c) {
    constexpr int k = (H == 2) ? (ta >> 1) : ta;
    constexpr int hoff = (H == 2) ? ((ta & 1) * 128) : 0;
    int i0 = c.snbr[c.row0 * KTAB + k];
    int i1 = c.snbr[c.row1 * KTAB + k];
    const char* b0 = c.finb + (size_t)i0 * c.CIB + hoff + c.lg16;
    const char* b1 = c.finb + (size_t)i1 * c.CIB + hoff + c.lg16;
    char* d = c.aslot + (ta % 6) * 4096;
    gload16(b0,      d);
    gload16(b0 + 64, d + 1024);
    gload16(b1,      d + 2048);
    gload16(b1 + 64, d + 3072);
}

// Event order: prologue [W0 W1 W2 | A0..A5]; body t issues W(t+3) then A(t+6).
// Wait at body t needs W(t) (issued body t-3) and A(t) (older). Younger set:
// A(t+3),W(t+1),A(t+4),W(t+2),A(t+5) -> NW = 4*3 + 2*2 = 16 steady.
template <int t, int KTAB, int H>
__device__ __forceinline__ void body(const CC<KTAB, H>& c, int lane, int lr,
                                     int wk0, int wk1, f32x4 (&acc)[2][4]) {
    constexpr int KT2 = CC<KTAB, H>::KT2;
    constexpr int NW =
        (t == 0) ? 20 : (t == 1) ? 22 : (t == 2) ? 24 :
        4 * (((t + 3 < KT2) ? 1 : 0) + ((t + 4 < KT2) ? 1 : 0) + ((t + 5 < KT2) ? 1 : 0)) +
        2 * (((t + 1 < KT2) ? 1 : 0) + ((t + 2 < KT2) ? 1 : 0));
    asm volatile("s_waitcnt vmcnt(%0)" :: "i"(NW) : "memory");
    __builtin_amdgcn_sched_barrier(0);
    __builtin_amdgcn_s_barrier();
    __builtin_amdgcn_sched_barrier(0);
    if constexpr (t + 3 < KT2) issue_w<t + 3>(c);

    // reads (compiler ds_read_b128, conflict-free / 2-way max)
    const char* as = c.aslot + (t % 6) * 4096 + lane * 16;
    bf16x8 a0 = *(const bf16x8*)(as);
    bf16x8 a1 = *(const bf16x8*)(as + 1024);
    bf16x8 a2 = *(const bf16x8*)(as + 2048);
    bf16x8 a3 = *(const bf16x8*)(as + 3072);
    const char* wsb = c.wbuf + (t & 3) * 8192 + lr * 128;
    bf16x8 w0[4], w1[4];
#pragma unroll
    for (int ct = 0; ct < 4; ++ct) {
        w0[ct] = *(const bf16x8*)(wsb + ct * 2048 + wk0);
        w1[ct] = *(const bf16x8*)(wsb + ct * 2048 + wk1);
    }
    asm volatile("s_waitcnt lgkmcnt(0)" ::: "memory");
    __builtin_amdgcn_sched_barrier(0);
    if constexpr (t + 6 < KT2) issue_a<t + 6>(c);

#pragma unroll
    for (int ct = 0; ct < 4; ++ct) {
        acc[0][ct] = __builtin_amdgcn_mfma_f32_16x16x32_bf16(a0, w0[ct], acc[0][ct], 0, 0, 0);
        acc[0][ct] = __builtin_amdgcn_mfma_f32_16x16x32_bf16(a1, w1[ct], acc[0][ct], 0, 0, 0);
        acc[1][ct] = __builtin_amdgcn_mfma_f32_16x16x32_bf16(a2, w0[ct], acc[1][ct], 0, 0, 0);
        acc[1][ct] = __builtin_amdgcn_mfma_f32_16x16x32_bf16(a3, w1[ct], acc[1][ct], 0, 0, 0);
    }
    if constexpr (t + 1 < KT2) body<t + 1>(c, lane, lr, wk0, wk1, acc);
}

// MODE 0: leaky(acc[+bias]) -> bf16 + fused stats. MODE 1: acc+bias+skip -> bf16.
template <int KTAB, int H, int MODE, bool HAS_BIAS>
__global__ __launch_bounds__(256, 1) void conv_kernel(
    const short* __restrict__ fin, const int* __restrict__ nbr,
    const short* __restrict__ wp, const float* __restrict__ bias,
    const float* __restrict__ skip, short* __restrict__ fout,
    int N, float* __restrict__ sums)
{
    __shared__ int snbr[128 * KTAB];
    __shared__ __align__(16) char wbuf[4 * 8192];
    __shared__ __align__(16) char abuf[4][6 * 4096];
    __shared__ float sred[128];

    const int tid = threadIdx.x;
    const int lane = tid & 63;
    const int wid = tid >> 6;
    const int lr = lane & 15;
    const int lg = lane >> 4;
    const int rowbase = blockIdx.x * 128;
    const int nrows = (N - rowbase < 128) ? (N - rowbase) : 128;

    for (int i = tid; i < nrows * KTAB; i += 256)
        snbr[i] = __builtin_nontemporal_load(&nbr[(size_t)rowbase * KTAB + i]);
    if (MODE == 0 && tid < 128) sred[tid] = 0.f;
    __syncthreads();   // full drain: vmcnt accounting starts clean

    const int rb0 = wid * 32 + lr;
    const int rb1 = wid * 32 + 16 + lr;

    CC<KTAB, H> c;
    c.finb = (const char*)fin;
    c.wpb = (const char*)wp;
    c.snbr = snbr;
    c.aslot = &abuf[wid][0];
    c.wbuf = wbuf;
    c.row0 = (rb0 < nrows ? rb0 : nrows - 1);
    c.row1 = (rb1 < nrows ? rb1 : nrows - 1);
    c.lg16 = lg * 16;
    // W stage: lane writes LDS phys (lane*16); logical source undoes XOR swizzle
    c.wsrc = wid * 2048 + (lane >> 3) * 128 + (((lane & 7) ^ ((lane >> 3) & 7)) << 4);
    c.wdst = wid * 2048;
    c.CIB = 64 * H * 2;

    // W read offsets: frag (ct,kc) at co*128 + ((kc*4+lg)^(lr&7))*16
    const int wk0 = ((lg) ^ (lr & 7)) << 4;
    const int wk1 = ((4 + lg) ^ (lr & 7)) << 4;

    f32x4 acc[2][4];
#pragma unroll
    for (int q = 0; q < 2; ++q)
#pragma unroll
        for (int ct = 0; ct < 4; ++ct) acc[q][ct] = (f32x4)(0.f);

    // prologue: W0 W1 W2, A0..A5
    issue_w<0>(c); issue_w<1>(c); issue_w<2>(c);
    issue_a<0>(c); issue_a<1>(c); issue_a<2>(c);
    issue_a<3>(c); issue_a<4>(c); issue_a<5>(c);
    body<0>(c, lane, lr, wk0, wk1, acc);

    // ---------------- epilogue ----------------
    float bia[4] = {0.f, 0.f, 0.f, 0.f};
    if (HAS_BIAS) {
#pragma unroll
        for (int ct = 0; ct < 4; ++ct) bia[ct] = bias[ct * 16 + lr];
    }
    float bsum[4] = {0.f, 0.f, 0.f, 0.f};
    float bsq[4] = {0.f, 0.f, 0.f, 0.f};
    const int wrow = wid * 32;
#pragma unroll
    for (int q = 0; q < 2; ++q) {
#pragma unroll
        for (int reg = 0; reg < 4; ++reg) {
            const int r = rowbase + wrow + q * 16 + lg * 4 + reg;
            const bool valid = r < N;
#pragma unroll
            for (int ct = 0; ct < 4; ++ct) {
                float v = acc[q][ct][reg];
                if (HAS_BIAS) v += bia[ct];
                if (MODE == 0) {
                    v = v > 0.f ? v : 0.01f * v;
                    if (valid) {
                        fout[(size_t)r * 64 + ct * 16 + lr] = f2bf(v);
                        bsum[ct] += v;
                        bsq[ct] += v * v;
                    }
                } else {
                    if (valid) {
                        v += skip[(size_t)r * 64 + ct * 16 + lr];
                        fout[(size_t)r * 64 + ct * 16 + lr] = f2bf(v);
                    }
                }
            }
        }
    }

    if (MODE == 0) {
#pragma unroll
        for (int ct = 0; ct < 4; ++ct) {
            float s = bsum[ct], q = bsq[ct];
            s += __shfl_xor(s, 16); s += __shfl_xor(s, 32);
            q += __shfl_xor(q, 16); q += __shfl_xor(q, 32);
            if (lg == 0) {
                atomicAdd(&sred[ct * 16 + lr], s);
                atomicAdd(&sred[64 + ct * 16 + lr], q);
            }
        }
        __syncthreads();
        if (tid < 128) atomicAdd(&sums[tid], sred[tid]);
    }
}

// -------------- BN scale/shift from sums --------------
__global__ void finalize_kernel(const float* __restrict__ sums, const float* __restrict__ g,
                                const float* __restrict__ b, float invN, float* __restrict__ ss) {
    int c = threadIdx.x;
    float mean = sums[c] * invN;
    float var = sums[64 + c] * invN - mean * mean;
    float sc = g[c] * rsqrtf(var + 1e-5f);
    ss[c] = sc;
    ss[64 + c] = b[c] - mean * sc;
}

// -------------- final BN apply -> fp32 output --------------
__global__ void final_norm_kernel(const short* __restrict__ in, const float* __restrict__ ss,
                                  float* __restrict__ out, int total) {
    int e = (blockIdx.x * blockDim.x + threadIdx.x) * 8;
    if (e >= total) return;
    bf16x8 v = *(const bf16x8*)(in + e);
    int c0 = e & 63;
#pragma unroll
    for (int j = 0; j < 8; ++j)
        out[e + j] = bf2f(v[j]) * ss[c0 + j] + ss[64 + c0 + j];
}

extern "C" void kernel_launch(void* const* d_in, const int* in_sizes, int n_in,
                              void* d_out, int out_size, void* d_ws, size_t ws_size,
                              hipStream_t stream) {
    const float* x    = (const float*)d_in[0];
    const float* skip = (const float*)d_in[1];
    const int* nbr1 = (const int*)d_in[2];
    const int* nbrU = (const int*)d_in[3];
    const int* nbr2 = (const int*)d_in[4];
    const int* nbr3 = (const int*)d_in[5];
    const int* nbr4 = (const int*)d_in[6];
    const float* W1 = (const float*)d_in[7];
    const float* WU = (const float*)d_in[8];
    const float* W2 = (const float*)d_in[9];
    const float* W3 = (const float*)d_in[10];
    const float* W4 = (const float*)d_in[11];
    const float* g1 = (const float*)d_in[12]; const float* b1 = (const float*)d_in[13];
    const float* g2 = (const float*)d_in[14]; const float* b2 = (const float*)d_in[15];
    const float* g3 = (const float*)d_in[16]; const float* b3 = (const float*)d_in[17];
    const float* g4 = (const float*)d_in[18]; const float* b4 = (const float*)d_in[19];

    const int Nl = in_sizes[0] / 128;  // 120000
    const int Nu = in_sizes[1] / 64;   // 240000

    char* ws = (char*)d_ws;
    size_t off = 0;
    auto alloc = [&](size_t bytes) -> char* {
        char* p = ws + off;
        off += (bytes + 255) & ~(size_t)255;
        return p;
    };
    const size_t fbig = (size_t)Nu * 64 * 2;
    const size_t xb = (size_t)Nl * 128 * 2;
    short* A = (short*)alloc(xb > fbig ? xb : fbig);
    short* B = (short*)alloc(fbig);
    short* C = (short*)alloc(fbig);
    short* Wp1 = (short*)alloc((size_t)54 * 8192);
    short* WpU = (short*)alloc((size_t)27 * 8192);
    short* Wp2 = (short*)alloc((size_t)9 * 8192);
    short* Wp3 = (short*)alloc((size_t)9 * 8192);
    short* Wp4 = (short*)alloc((size_t)27 * 8192);
    float* sums = (float*)alloc((512 + 192) * sizeof(float));
    float* biasU = sums + 512;
    float* bias3 = sums + 576;
    float* bias4 = sums + 640;
    float* ss = (float*)alloc(4 * 128 * sizeof(float));

    hipMemsetAsync(sums, 0, (512 + 192) * sizeof(float), stream);

    cast_kernel<<<(Nl * 128 / 8 + 255) / 256, 256, 0, stream>>>(x, A, Nl * 128);
    pack_w_kernel<2><<<(54 * 4096 + 255) / 256, 256, 0, stream>>>(W1, Wp1, nullptr, 54 * 4096);
    pack_w_kernel<1><<<(9 * 4096 + 255) / 256, 256, 0, stream>>>(W2, Wp2, nullptr, 9 * 4096);

    const int gl = (Nl + 127) / 128;
    const int gu = (Nu + 127) / 128;

    // stage 1: conv1 (CI=128 -> H=2, K=27) + leaky + stats  [A -> B]
    conv_kernel<27, 2, 0, false><<<gl, 256, 0, stream>>>(A, nbr1, Wp1, nullptr, nullptr, B, Nl, sums + 0);
    finalize_kernel<<<1, 64, 0, stream>>>(sums + 0, g1, b1, 1.f / Nl, ss + 0);
    pack_w_kernel<1><<<(27 * 4096 + 255) / 256, 256, 0, stream>>>(WU, WpU, ss + 0, 27 * 4096);
    bias_kernel<<<27, 64, 0, stream>>>(WU, ss + 0, 64, biasU);

    // stage 2: inverse conv (K=27) + bias + skip  [B -> C]
    conv_kernel<27, 1, 1, true><<<gu, 256, 0, stream>>>(B, nbrU, WpU, biasU, skip, C, Nu, nullptr);

    // stage 3: conv2 (K=9) + leaky + stats  [C -> A]
    conv_kernel<9, 1, 0, false><<<gu, 256, 0, stream>>>(C, nbr2, Wp2, nullptr, nullptr, A, Nu, sums + 128);
    finalize_kernel<<<1, 64, 0, stream>>>(sums + 128, g2, b2, 1.f / Nu, ss + 128);
    pack_w_kernel<1><<<(9 * 4096 + 255) / 256, 256, 0, stream>>>(W3, Wp3, ss + 128, 9 * 4096);
    bias_kernel<<<9, 64, 0, stream>>>(W3, ss + 128, 64, bias3);

    // stage 4: conv3 (K=9) + bias + leaky + stats  [A -> B]
    conv_kernel<9, 1, 0, true><<<gu, 256, 0, stream>>>(A, nbr3, Wp3, bias3, nullptr, B, Nu, sums + 256);
    finalize_kernel<<<1, 64, 0, stream>>>(sums + 256, g3, b3, 1.f / Nu, ss + 256);
    pack_w_kernel<1><<<(27 * 4096 + 255) / 256, 256, 0, stream>>>(W4, Wp4, ss + 256, 27 * 4096);
    bias_kernel<<<27, 64, 0, stream>>>(W4, ss + 256, 64, bias4);

    // stage 5: conv4 (K=27) + bias + leaky + stats  [B -> C]
    conv_kernel<27, 1, 0, true><<<gu, 256, 0, stream>>>(B, nbr4, Wp4, bias4, nullptr, C, Nu, sums + 384);
    finalize_kernel<<<1, 64, 0, stream>>>(sums + 384, g4, b4, 1.f / Nu, ss + 384);

    final_norm_kernel<<<(Nu * 64 / 8 + 255) / 256, 256, 0, stream>>>(C, ss + 384, (float*)d_out, Nu * 64);
}

// Round 10
// 773.353 us; speedup vs baseline: 1.3907x; 1.3857x over previous
//
#include <hip/hip_runtime.h>
#include <hip/hip_bf16.h>

// UpBlock: 5 sparse gather-GEMM convs + LeakyReLU + BatchNorm + residual.
// R10: R4 occupancy (2 blocks/CU) + true depth-3 gather pipeline.
// 96-row/3-wave blocks; A depth-3 per-wave LDS slots; W staged as 16 KB
// pair-slots ONE pair ahead (older in vmcnt queue than co-waited A);
// barrier only at pair start, before the per-wave counted vmcnt.

typedef __attribute__((ext_vector_type(8))) short bf16x8;
typedef __attribute__((ext_vector_type(4))) float f32x4;

__device__ __forceinline__ short f2bf(float f) {
    union { float f; unsigned u; } v; v.f = f;
    unsigned r = v.u + 0x7fffu + ((v.u >> 16) & 1u);
    return (short)(r >> 16);
}
__device__ __forceinline__ float bf2f(short s) {
    union { unsigned u; float f; } v;
    v.u = ((unsigned)(unsigned short)s) << 16;
    return v.f;
}

__device__ __forceinline__ void gload16(const void* g, void* l) {
    __builtin_amdgcn_global_load_lds(
        (const __attribute__((address_space(1))) char*)g,
        (__attribute__((address_space(3))) char*)l, 16, 0, 0);
}

// ---------------- cast fp32 -> bf16 ----------------
__global__ void cast_kernel(const float* __restrict__ in, short* __restrict__ out, int total) {
    int e = (blockIdx.x * blockDim.x + threadIdx.x) * 8;
    if (e >= total) return;
    bf16x8 r;
#pragma unroll
    for (int j = 0; j < 8; ++j) r[j] = f2bf(in[e + j]);
    *(bf16x8*)(out + e) = r;
}

// ---- pack W[k][ci][co] -> Wp[tap'][co][ci'] bf16 (tap' = CI-64 sub-tap) ----
template <int H>  // H = CI/64
__global__ void pack_w_kernel(const float* __restrict__ w, short* __restrict__ wp,
                              const float* __restrict__ ss, int total) {
    int t = blockIdx.x * blockDim.x + threadIdx.x;
    if (t >= total) return;
    int ci2 = t & 63;
    int co = (t >> 6) & 63;
    int tap = t >> 12;
    int k = tap / H, half = tap % H;
    int ci = half * 64 + ci2;
    float v = w[(k * (64 * H) + ci) * 64 + co];
    if (ss) v *= ss[ci];
    wp[t] = f2bf(v);
}

// ------ bias[co] += sum_ci sh[ci]*W[k][ci][co]; one block per tap k ------
__global__ void bias_kernel(const float* __restrict__ w, const float* __restrict__ ss,
                            int CI, float* __restrict__ bias) {
    int k = blockIdx.x;
    int co = threadIdx.x;
    float acc = 0.f;
    for (int ci = 0; ci < CI; ++ci)
        acc += ss[64 + ci] * w[(k * CI + ci) * 64 + co];
    atomicAdd(&bias[co], acc);
}

// ================= gather-GEMM conv =================
template <int KTAB, int H>
struct CC {
    static constexpr int KT2 = KTAB * H;           // sub-taps
    static constexpr int NP = (KT2 + 1) / 2;       // pairs
    const char* finb;
    const char* wpb;
    const int* snbr;
    char* aslot;      // my wave's 3 A slots (3 x 4 KB)
    char* wbuf;       // 2 W pair-slots (2 x 16 KB), block-shared
    int row0, row1;
    int lg16;         // lg*16
    int widx64;       // wid*64 (uniform)
    int lane;
    int CIB;          // feature row bytes
};

// stage W pair p into slot p&1 (6 modulo-mapped insts/wave; 3 waves cover
// 1024 16B-chunks with 2 benign duplicates). Source pre-permuted so LDS
// phys chunk (co,j) holds W[co][j ^ (co&7)] (XOR bank swizzle).
template <int p, int KTAB, int H>
__device__ __forceinline__ void issue_w(const CC<KTAB, H>& c) {
#pragma unroll
    for (int r = 0; r < 6; ++r) {
        const int slotbase = ((r * 192) + c.widx64) & 1023;   // uniform, 64-aligned
        const int s_idx = slotbase + c.lane;
        const int co = (s_idx >> 3) & 63;
        const int j = s_idx & 7;
        const int half = s_idx >> 9;
        const char* src = c.wpb + (size_t)p * 16384 + half * 8192 + co * 128
                          + ((j ^ (co & 7)) << 4);
        char* dst = c.wbuf + (p & 1) * 16384 + slotbase * 16;
        gload16(src, dst);
    }
}

// gather A sub-tap ta into my slot ta%3 (4 insts: 2 row-tiles x 2 ci-chunks)
template <int ta, int KTAB, int H>
__device__ __forceinline__ void issue_a(const CC<KTAB, H>& c) {
    constexpr int k = (H == 2) ? (ta >> 1) : ta;
    constexpr int hoff = (H == 2) ? ((ta & 1) * 128) : 0;
    int i0 = c.snbr[c.row0 * KTAB + k];
    int i1 = c.snbr[c.row1 * KTAB + k];
    const char* b0 = c.finb + (size_t)i0 * c.CIB + hoff + c.lg16;
    const char* b1 = c.finb + (size_t)i1 * c.CIB + hoff + c.lg16;
    char* d = c.aslot + (ta % 3) * 4096;
    gload16(b0,      d);
    gload16(b0 + 64, d + 1024);
    gload16(b1,      d + 2048);
    gload16(b1 + 2048 - 1984, d + 3072); // b1+64
}

// Queue (per wave): prologue [W0(6) A0 A1 A2]; even t=2p: issue W(p+1)(6)
// then A(t+3)(4); odd t: issue A(t+3)(4).
// Waits: even t needs A(t),W(p): younger = A(t+1),A(t+2) -> 8.
//        odd t needs A(t): younger = A(t+1),W(p+1),A(t+2) -> 14.
template <int t, int KTAB, int H>
__device__ __forceinline__ void body(const CC<KTAB, H>& c, int lane, int lr,
                                     int wk0, int wk1, f32x4 (&acc)[2][4]) {
    constexpr int KT2 = CC<KTAB, H>::KT2;
    constexpr int NW = ((t & 1) == 0)
        ? (4 * ((t + 1 < KT2) ? 1 : 0) + 4 * ((t + 2 < KT2) ? 1 : 0))
        : (10 * ((t + 1 < KT2) ? 1 : 0) + 4 * ((t + 2 < KT2) ? 1 : 0));
    if constexpr ((t & 1) == 0) {
        __builtin_amdgcn_sched_barrier(0);
        __builtin_amdgcn_s_barrier();        // pair boundary: W slot reuse safe
        __builtin_amdgcn_sched_barrier(0);
    }
    asm volatile("s_waitcnt vmcnt(%0)" :: "i"(NW) : "memory");
    __builtin_amdgcn_sched_barrier(0);
    if constexpr ((t & 1) == 0) {
        if constexpr (t + 2 < KT2) issue_w<t / 2 + 1>(c);
    }

    // LDS reads: A from own slot (linear), W from swizzled pair slot
    const char* as = c.aslot + (t % 3) * 4096 + lane * 16;
    bf16x8 a0 = *(const bf16x8*)(as);
    bf16x8 a1 = *(const bf16x8*)(as + 1024);
    bf16x8 a2 = *(const bf16x8*)(as + 2048);
    bf16x8 a3 = *(const bf16x8*)(as + 3072);
    const char* wt = c.wbuf + ((t >> 1) & 1) * 16384 + (t & 1) * 8192 + lr * 128;
    bf16x8 w0[4], w1[4];
#pragma unroll
    for (int ct = 0; ct < 4; ++ct) {
        w0[ct] = *(const bf16x8*)(wt + ct * 2048 + wk0);
        w1[ct] = *(const bf16x8*)(wt + ct * 2048 + wk1);
    }
    asm volatile("s_waitcnt lgkmcnt(0)" ::: "memory");
    __builtin_amdgcn_sched_barrier(0);
    if constexpr (t + 3 < KT2) issue_a<t + 3>(c);

#pragma unroll
    for (int ct = 0; ct < 4; ++ct) {
        acc[0][ct] = __builtin_amdgcn_mfma_f32_16x16x32_bf16(a0, w0[ct], acc[0][ct], 0, 0, 0);
        acc[0][ct] = __builtin_amdgcn_mfma_f32_16x16x32_bf16(a1, w1[ct], acc[0][ct], 0, 0, 0);
        acc[1][ct] = __builtin_amdgcn_mfma_f32_16x16x32_bf16(a2, w0[ct], acc[1][ct], 0, 0, 0);
        acc[1][ct] = __builtin_amdgcn_mfma_f32_16x16x32_bf16(a3, w1[ct], acc[1][ct], 0, 0, 0);
    }
    if constexpr (t + 1 < KT2) body<t + 1>(c, lane, lr, wk0, wk1, acc);
}

// MODE 0: leaky(acc[+bias]) -> bf16 + fused stats. MODE 1: acc+bias+skip -> bf16.
template <int KTAB, int H, int MODE, bool HAS_BIAS>
__global__ __launch_bounds__(192, 2) void conv_kernel(
    const short* __restrict__ fin, const int* __restrict__ nbr,
    const short* __restrict__ wp, const float* __restrict__ bias,
    const float* __restrict__ skip, short* __restrict__ fout,
    int N, float* __restrict__ sums)
{
    __shared__ int snbr[96 * KTAB];
    __shared__ __align__(16) char wbuf[2 * 16384];     // W pair double buffer
    __shared__ __align__(16) char abuf[3][3 * 4096];   // per-wave A slots
    __shared__ float sred[128];

    const int tid = threadIdx.x;
    const int lane = tid & 63;
    const int wid = tid >> 6;
    const int lr = lane & 15;
    const int lg = lane >> 4;
    const int rowbase = blockIdx.x * 96;
    const int nrows = (N - rowbase < 96) ? (N - rowbase) : 96;

    for (int i = tid; i < nrows * KTAB; i += 192)
        snbr[i] = __builtin_nontemporal_load(&nbr[(size_t)rowbase * KTAB + i]);
    if (MODE == 0 && tid < 128) sred[tid] = 0.f;
    __syncthreads();   // full drain: vmcnt accounting starts clean

    const int rb0 = wid * 32 + lr;
    const int rb1 = wid * 32 + 16 + lr;

    CC<KTAB, H> c;
    c.finb = (const char*)fin;
    c.wpb = (const char*)wp;
    c.snbr = snbr;
    c.aslot = &abuf[wid][0];
    c.wbuf = wbuf;
    c.row0 = (rb0 < nrows ? rb0 : nrows - 1);
    c.row1 = (rb1 < nrows ? rb1 : nrows - 1);
    c.lg16 = lg * 16;
    c.widx64 = wid * 64;
    c.lane = lane;
    c.CIB = 64 * H * 2;

    // W read offsets: frag (s,lg) of row co at co*128 + ((s*4+lg)^(co&7))*16
    const int wk0 = ((lg) ^ (lr & 7)) << 4;
    const int wk1 = ((4 + lg) ^ (lr & 7)) << 4;

    f32x4 acc[2][4];
#pragma unroll
    for (int q = 0; q < 2; ++q)
#pragma unroll
        for (int ct = 0; ct < 4; ++ct) acc[q][ct] = (f32x4)(0.f);

    // prologue: W0 (oldest), A0 A1 A2
    issue_w<0>(c);
    issue_a<0>(c); issue_a<1>(c); issue_a<2>(c);
    body<0>(c, lane, lr, wk0, wk1, acc);

    // ---------------- epilogue ----------------
    float bia[4] = {0.f, 0.f, 0.f, 0.f};
    if (HAS_BIAS) {
#pragma unroll
        for (int ct = 0; ct < 4; ++ct) bia[ct] = bias[ct * 16 + lr];
    }
    float bsum[4] = {0.f, 0.f, 0.f, 0.f};
    float bsq[4] = {0.f, 0.f, 0.f, 0.f};
    const int wrow = wid * 32;
#pragma unroll
    for (int q = 0; q < 2; ++q) {
#pragma unroll
        for (int reg = 0; reg < 4; ++reg) {
            const int r = rowbase + wrow + q * 16 + lg * 4 + reg;
            const bool valid = r < N;
#pragma unroll
            for (int ct = 0; ct < 4; ++ct) {
                float v = acc[q][ct][reg];
                if (HAS_BIAS) v += bia[ct];
                if (MODE == 0) {
                    v = v > 0.f ? v : 0.01f * v;
                    if (valid) {
                        fout[(size_t)r * 64 + ct * 16 + lr] = f2bf(v);
                        bsum[ct] += v;
                        bsq[ct] += v * v;
                    }
                } else {
                    if (valid) {
                        v += skip[(size_t)r * 64 + ct * 16 + lr];
                        fout[(size_t)r * 64 + ct * 16 + lr] = f2bf(v);
                    }
                }
            }
        }
    }

    if (MODE == 0) {
#pragma unroll
        for (int ct = 0; ct < 4; ++ct) {
            float s = bsum[ct], q = bsq[ct];
            s += __shfl_xor(s, 16); s += __shfl_xor(s, 32);
            q += __shfl_xor(q, 16); q += __shfl_xor(q, 32);
            if (lg == 0) {
                atomicAdd(&sred[ct * 16 + lr], s);
                atomicAdd(&sred[64 + ct * 16 + lr], q);
            }
        }
        __syncthreads();
        if (tid < 128) atomicAdd(&sums[tid], sred[tid]);
    }
}

// -------------- BN scale/shift from sums --------------
__global__ void finalize_kernel(const float* __restrict__ sums, const float* __restrict__ g,
                                const float* __restrict__ b, float invN, float* __restrict__ ss) {
    int c = threadIdx.x;
    float mean = sums[c] * invN;
    float var = sums[64 + c] * invN - mean * mean;
    float sc = g[c] * rsqrtf(var + 1e-5f);
    ss[c] = sc;
    ss[64 + c] = b[c] - mean * sc;
}

// -------------- final BN apply -> fp32 output --------------
__global__ void final_norm_kernel(const short* __restrict__ in, const float* __restrict__ ss,
                                  float* __restrict__ out, int total) {
    int e = (blockIdx.x * blockDim.x + threadIdx.x) * 8;
    if (e >= total) return;
    bf16x8 v = *(const bf16x8*)(in + e);
    int c0 = e & 63;
#pragma unroll
    for (int j = 0; j < 8; ++j)
        out[e + j] = bf2f(v[j]) * ss[c0 + j] + ss[64 + c0 + j];
}

extern "C" void kernel_launch(void* const* d_in, const int* in_sizes, int n_in,
                              void* d_out, int out_size, void* d_ws, size_t ws_size,
                              hipStream_t stream) {
    const float* x    = (const float*)d_in[0];
    const float* skip = (const float*)d_in[1];
    const int* nbr1 = (const int*)d_in[2];
    const int* nbrU = (const int*)d_in[3];
    const int* nbr2 = (const int*)d_in[4];
    const int* nbr3 = (const int*)d_in[5];
    const int* nbr4 = (const int*)d_in[6];
    const float* W1 = (const float*)d_in[7];
    const float* WU = (const float*)d_in[8];
    const float* W2 = (const float*)d_in[9];
    const float* W3 = (const float*)d_in[10];
    const float* W4 = (const float*)d_in[11];
    const float* g1 = (const float*)d_in[12]; const float* b1 = (const float*)d_in[13];
    const float* g2 = (const float*)d_in[14]; const float* b2 = (const float*)d_in[15];
    const float* g3 = (const float*)d_in[16]; const float* b3 = (const float*)d_in[17];
    const float* g4 = (const float*)d_in[18]; const float* b4 = (const float*)d_in[19];

    const int Nl = in_sizes[0] / 128;  // 120000
    const int Nu = in_sizes[1] / 64;   // 240000

    char* ws = (char*)d_ws;
    size_t off = 0;
    auto alloc = [&](size_t bytes) -> char* {
        char* p = ws + off;
        off += (bytes + 255) & ~(size_t)255;
        return p;
    };
    const size_t fbig = (size_t)Nu * 64 * 2;
    const size_t xb = (size_t)Nl * 128 * 2;
    short* A = (short*)alloc(xb > fbig ? xb : fbig);
    short* B = (short*)alloc(fbig);
    short* C = (short*)alloc(fbig);
    // W buffers: pair-slot granularity (16 KB per pair), +1 phantom subtap ok
    short* Wp1 = (short*)alloc((size_t)27 * 16384);  // KT2=54 -> 27 pairs
    short* WpU = (short*)alloc((size_t)14 * 16384);  // KT2=27 -> 14 pairs
    short* Wp2 = (short*)alloc((size_t)5 * 16384);   // KT2=9  -> 5 pairs
    short* Wp3 = (short*)alloc((size_t)5 * 16384);
    short* Wp4 = (short*)alloc((size_t)14 * 16384);
    float* sums = (float*)alloc((512 + 192) * sizeof(float));
    float* biasU = sums + 512;
    float* bias3 = sums + 576;
    float* bias4 = sums + 640;
    float* ss = (float*)alloc(4 * 128 * sizeof(float));

    hipMemsetAsync(sums, 0, (512 + 192) * sizeof(float), stream);

    cast_kernel<<<(Nl * 128 / 8 + 255) / 256, 256, 0, stream>>>(x, A, Nl * 128);
    pack_w_kernel<2><<<(54 * 4096 + 255) / 256, 256, 0, stream>>>(W1, Wp1, nullptr, 54 * 4096);
    pack_w_kernel<1><<<(9 * 4096 + 255) / 256, 256, 0, stream>>>(W2, Wp2, nullptr, 9 * 4096);

    const int gl = (Nl + 95) / 96;
    const int gu = (Nu + 95) / 96;

    // stage 1: conv1 (CI=128 -> H=2, K=27) + leaky + stats  [A -> B]
    conv_kernel<27, 2, 0, false><<<gl, 192, 0, stream>>>(A, nbr1, Wp1, nullptr, nullptr, B, Nl, sums + 0);
    finalize_kernel<<<1, 64, 0, stream>>>(sums + 0, g1, b1, 1.f / Nl, ss + 0);
    pack_w_kernel<1><<<(27 * 4096 + 255) / 256, 256, 0, stream>>>(WU, WpU, ss + 0, 27 * 4096);
    bias_kernel<<<27, 64, 0, stream>>>(WU, ss + 0, 64, biasU);

    // stage 2: inverse conv (K=27) + bias + skip  [B -> C]
    conv_kernel<27, 1, 1, true><<<gu, 192, 0, stream>>>(B, nbrU, WpU, biasU, skip, C, Nu, nullptr);

    // stage 3: conv2 (K=9) + leaky + stats  [C -> A]
    conv_kernel<9, 1, 0, false><<<gu, 192, 0, stream>>>(C, nbr2, Wp2, nullptr, nullptr, A, Nu, sums + 128);
    finalize_kernel<<<1, 64, 0, stream>>>(sums + 128, g2, b2, 1.f / Nu, ss + 128);
    pack_w_kernel<1><<<(9 * 4096 + 255) / 256, 256, 0, stream>>>(W3, Wp3, ss + 128, 9 * 4096);
    bias_kernel<<<9, 64, 0, stream>>>(W3, ss + 128, 64, bias3);

    // stage 4: conv3 (K=9) + bias + leaky + stats  [A -> B]
    conv_kernel<9, 1, 0, true><<<gu, 192, 0, stream>>>(A, nbr3, Wp3, bias3, nullptr, B, Nu, sums + 256);
    finalize_kernel<<<1, 64, 0, stream>>>(sums + 256, g3, b3, 1.f / Nu, ss + 256);
    pack_w_kernel<1><<<(27 * 4096 + 255) / 256, 256, 0, stream>>>(W4, Wp4, ss + 256, 27 * 4096);
    bias_kernel<<<27, 64, 0, stream>>>(W4, ss + 256, 64, bias4);

    // stage 5: conv4 (K=27) + bias + leaky + stats  [B -> C]
    conv_kernel<27, 1, 0, true><<<gu, 192, 0, stream>>>(B, nbr4, Wp4, bias4, nullptr, C, Nu, sums + 384);
    finalize_kernel<<<1, 64, 0, stream>>>(sums + 384, g4, b4, 1.f / Nu, ss + 384);

    final_norm_kernel<<<(Nu * 64 / 8 + 255) / 256, 256, 0, stream>>>(C, ss + 384, (float*)d_out, Nu * 64);
}